// Round 1
// baseline (399.968 us; speedup 1.0000x reference)
//
#include <hip/hip_runtime.h>
#include <math.h>

// Problem constants (B, V, H, NI, E) = (512, 50, 768, 8, 2)
#define B_  512
#define V_  50
#define H_  768
#define NI_ 8
#define M_  (B_ * NI_)   // 4096 MLP rows

__device__ __forceinline__ float gelu_exact(float x) {
    // jax.nn.gelu(approximate=False) = 0.5*x*(1+erf(x/sqrt(2)))
    return 0.5f * x * (1.0f + erff(x * 0.7071067811865476f));
}

// ---------------------------------------------------------------------------
// 1) copy variable_states -> out (float4 grid-stride)
// ---------------------------------------------------------------------------
__global__ __launch_bounds__(256) void copy_kernel(const float4* __restrict__ in,
                                                   float4* __restrict__ out, int n4) {
    int i = blockIdx.x * blockDim.x + threadIdx.x;
    int stride = gridDim.x * blockDim.x;
    for (; i < n4; i += stride) out[i] = in[i];
}

// ---------------------------------------------------------------------------
// 2) Tiled fp32 GEMM: C[M,N] = act(A[M,K] @ W[K,N] + bias[N])
//    GATHER=1: A row r=(b,i) is the virtual row [vs[b, idxc(b,i), :] ‖ iv[b, i, :]]
//    BM=BN=64, BK=16, 256 threads, 4x4 microtile per thread.
// ---------------------------------------------------------------------------
template <int ACT, int GATHER>
__global__ __launch_bounds__(256) void gemm_tiled(
    const float* __restrict__ A, const float* __restrict__ W,
    const float* __restrict__ bias, float* __restrict__ C,
    int M, int N, int K,
    const float* __restrict__ vs, const float* __restrict__ iv,
    const int* __restrict__ idx) {
    const int BM = 64, BN = 64, BK = 16;
    __shared__ float As[BK][BM + 4];
    __shared__ float Bs[BK][BN + 4];

    const int tid = threadIdx.x;
    const int tx = tid % 16;  // n dimension
    const int ty = tid / 16;  // m dimension
    const int row0 = blockIdx.y * BM;
    const int col0 = blockIdx.x * BN;

    float acc[4][4] = {};

    for (int k0 = 0; k0 < K; k0 += BK) {
        // A tile: BM x BK = 1024 elems, 4 per thread
#pragma unroll
        for (int e = 0; e < 4; ++e) {
            int li = tid + e * 256;
            int m = li / BK;
            int kk = li % BK;
            int gm = row0 + m;
            int gk = k0 + kk;
            float v;
            if (GATHER) {
                int b = gm / NI_;
                int ii = gm - b * NI_;
                int id = idx[b * NI_ + ii];
                id = min(max(id, 0), V_ - 1);
                v = (gk < H_)
                        ? vs[(size_t)b * V_ * H_ + (size_t)id * H_ + gk]
                        : iv[(size_t)b * NI_ * H_ + (size_t)ii * H_ + (gk - H_)];
            } else {
                v = A[(size_t)gm * K + gk];
            }
            As[kk][m] = v;
        }
        // B tile: BK x BN = 1024 elems
#pragma unroll
        for (int e = 0; e < 4; ++e) {
            int li = tid + e * 256;
            int kk = li / BN;
            int n = li - kk * BN;
            Bs[kk][n] = W[(size_t)(k0 + kk) * N + (col0 + n)];
        }
        __syncthreads();

#pragma unroll
        for (int kk = 0; kk < BK; ++kk) {
            float a[4], b[4];
#pragma unroll
            for (int j = 0; j < 4; ++j) a[j] = As[kk][ty * 4 + j];
#pragma unroll
            for (int j = 0; j < 4; ++j) b[j] = Bs[kk][tx * 4 + j];
#pragma unroll
            for (int i = 0; i < 4; ++i)
#pragma unroll
                for (int j = 0; j < 4; ++j) acc[i][j] = fmaf(a[i], b[j], acc[i][j]);
        }
        __syncthreads();
    }

#pragma unroll
    for (int i = 0; i < 4; ++i) {
        int gm = row0 + ty * 4 + i;
#pragma unroll
        for (int j = 0; j < 4; ++j) {
            int gn = col0 + tx * 4 + j;
            float v = acc[i][j] + bias[gn];
            if (ACT) v = gelu_exact(v);
            C[(size_t)gm * N + gn] = v;
        }
    }
}

// ---------------------------------------------------------------------------
// 3) gate[r] = sigmoid(dot(g1[r,:], Wg2) + bg2)
// ---------------------------------------------------------------------------
__global__ __launch_bounds__(256) void gate_kernel(const float* __restrict__ g1,
                                                   const float* __restrict__ Wg2,
                                                   const float* __restrict__ bg2,
                                                   float* __restrict__ gate) {
    int r = blockIdx.x;
    const float* row = g1 + (size_t)r * H_;
    float s = 0.f;
    for (int k = threadIdx.x; k < H_; k += 256) s += row[k] * Wg2[k];
#pragma unroll
    for (int off = 32; off > 0; off >>= 1) s += __shfl_down(s, off);
    __shared__ float red[4];
    int lane = threadIdx.x & 63;
    int w = threadIdx.x >> 6;
    if (lane == 0) red[w] = s;
    __syncthreads();
    if (threadIdx.x == 0) {
        float t = red[0] + red[1] + red[2] + red[3] + bg2[0];
        gate[r] = 1.f / (1.f + expf(-t));
    }
}

// ---------------------------------------------------------------------------
// 4) scatter: out[b, idxc, :] = orig*(1-g) + iv*g  (last-write-wins over i)
// ---------------------------------------------------------------------------
__global__ __launch_bounds__(256) void scatter_kernel(const float* __restrict__ vs,
                                                      const float* __restrict__ iv,
                                                      const int* __restrict__ idx,
                                                      const float* __restrict__ gate,
                                                      float* __restrict__ out) {
    int blk = blockIdx.x;  // 0 .. B*NI-1
    int b = blk / NI_;
    int i = blk - b * NI_;
    int myid = idx[b * NI_ + i];
    bool valid = (myid >= 0) && (myid < V_);
    if (!valid) return;  // invalid entries are exact no-ops
    // skip if a later valid intervention targets the same slot (last-write-wins)
    for (int j = i + 1; j < NI_; ++j) {
        int oid = idx[b * NI_ + j];
        if (oid >= 0 && oid < V_ && oid == myid) return;
    }
    float g = gate[blk];
    const float* orig = vs + (size_t)b * V_ * H_ + (size_t)myid * H_;
    const float* ivr = iv + (size_t)b * NI_ * H_ + (size_t)i * H_;
    float* dst = out + (size_t)b * V_ * H_ + (size_t)myid * H_;
    for (int h = threadIdx.x; h < H_; h += 256) {
        float o = orig[h];
        float v = ivr[h];
        dst[h] = o * (1.f - g) + v * g;
    }
}

// ---------------------------------------------------------------------------
extern "C" void kernel_launch(void* const* d_in, const int* in_sizes, int n_in,
                              void* d_out, int out_size, void* d_ws, size_t ws_size,
                              hipStream_t stream) {
    const float* vs  = (const float*)d_in[0];
    // d_in[1] = edge_probs: unused by the reference
    const float* iv  = (const float*)d_in[2];
    const float* W1  = (const float*)d_in[3];
    const float* b1  = (const float*)d_in[4];
    const float* W2  = (const float*)d_in[5];
    const float* b2  = (const float*)d_in[6];
    const float* Wg1 = (const float*)d_in[7];
    const float* bg1 = (const float*)d_in[8];
    const float* Wg2 = (const float*)d_in[9];
    const float* bg2 = (const float*)d_in[10];
    const int*   idx = (const int*)d_in[11];
    float* out = (float*)d_out;

    // workspace layout (floats): h1[M*H] | enc[M*H] | gate[M]
    float* h1   = (float*)d_ws;
    float* enc  = h1 + (size_t)M_ * H_;
    float* gate = enc + (size_t)M_ * H_;

    // 1) copy states to out
    int n4 = (B_ * V_ * H_) / 4;
    copy_kernel<<<2048, 256, 0, stream>>>((const float4*)vs, (float4*)out, n4);

    dim3 grid(H_ / 64, M_ / 64);  // (12, 64)
    // 2) h1 = gelu([orig‖iv] @ W1 + b1)   K=1536
    gemm_tiled<1, 1><<<grid, 256, 0, stream>>>(nullptr, W1, b1, h1, M_, H_, 2 * H_, vs, iv, idx);
    // 3) enc = h1 @ W2 + b2               K=768
    gemm_tiled<0, 0><<<grid, 256, 0, stream>>>(h1, W2, b2, enc, M_, H_, H_, nullptr, nullptr, nullptr);
    // 4) g1 = gelu(enc @ Wg1 + bg1)  (overwrites h1)
    gemm_tiled<1, 0><<<grid, 256, 0, stream>>>(enc, Wg1, bg1, h1, M_, H_, H_, nullptr, nullptr, nullptr);
    // 5) gate = sigmoid(g1 @ Wg2 + bg2)
    gate_kernel<<<M_, 256, 0, stream>>>(h1, Wg2, bg2, gate);
    // 6) scatter blended rows into out
    scatter_kernel<<<M_, 256, 0, stream>>>(vs, iv, idx, gate, out);
}

// Round 2
// 144.679 us; speedup vs baseline: 2.7645x; 2.7645x over previous
//
#include <hip/hip_runtime.h>
#include <math.h>

// Problem constants (B, V, H, NI, E) = (512, 50, 768, 8, 2)
#define B_  512
#define V_  50
#define H_  768
#define NI_ 8
#define M_  (B_ * NI_)   // 4096 MLP rows
#define K1_ (2 * H_)     // 1536

using f32x4 = __attribute__((ext_vector_type(4))) float;
using s16x8 = __attribute__((ext_vector_type(8))) short;

__device__ __forceinline__ float gelu_exact(float x) {
    return 0.5f * x * (1.0f + erff(x * 0.7071067811865476f));
}

__device__ __forceinline__ short f2bf(float f) {
    union { float f; unsigned u; } v; v.f = f;
    unsigned r = (v.u + 0x7fffu + ((v.u >> 16) & 1u)) >> 16;  // RNE
    return (short)r;
}
__device__ __forceinline__ float bf2f(short h) {
    union { unsigned u; float f; } v; v.u = ((unsigned)(unsigned short)h) << 16;
    return v.f;
}

// ---------------------------------------------------------------------------
// 1) copy variable_states -> out (float4 grid-stride)
// ---------------------------------------------------------------------------
__global__ __launch_bounds__(256) void copy_kernel(const float4* __restrict__ in,
                                                   float4* __restrict__ out, int n4) {
    int i = blockIdx.x * blockDim.x + threadIdx.x;
    int stride = gridDim.x * blockDim.x;
    for (; i < n4; i += stride) out[i] = in[i];
}

// ---------------------------------------------------------------------------
// 2) convert fp32 W[K][N] -> bf16 Wt[N][K] (transpose via LDS)
// ---------------------------------------------------------------------------
__global__ __launch_bounds__(256) void convert_transpose(const float* __restrict__ W,
                                                         short* __restrict__ Wt,
                                                         int K, int N) {
    __shared__ short s[64][65];
    int k0 = blockIdx.y * 64, n0 = blockIdx.x * 64;
    int tid = threadIdx.x;
#pragma unroll
    for (int e = 0; e < 16; ++e) {
        int li = tid + e * 256;
        int kk = li >> 6, nn = li & 63;
        s[kk][nn] = f2bf(W[(size_t)(k0 + kk) * N + n0 + nn]);
    }
    __syncthreads();
#pragma unroll
    for (int e = 0; e < 16; ++e) {
        int li = tid + e * 256;
        int nn = li >> 6, kk = li & 63;
        Wt[(size_t)(n0 + nn) * K + k0 + kk] = s[kk][nn];
    }
}

// ---------------------------------------------------------------------------
// 3) gather X[r][0:768]=vs[b,idxc], X[r][768:1536]=iv[b,i]  (bf16)
// ---------------------------------------------------------------------------
__global__ __launch_bounds__(192) void gather_x(const float* __restrict__ vs,
                                                const float* __restrict__ iv,
                                                const int* __restrict__ idx,
                                                short* __restrict__ X) {
    int r = blockIdx.x;              // 0..4095
    int b = r >> 3;
    int id = idx[r];
    id = min(max(id, 0), V_ - 1);
    const float4* s1 = (const float4*)(vs + ((size_t)b * V_ + id) * H_);
    const float4* s2 = (const float4*)(iv + (size_t)r * H_);
    int t = threadIdx.x;             // 0..191
    float4 a = s1[t];
    float4 c = s2[t];
    short4 oa, oc;
    oa.x = f2bf(a.x); oa.y = f2bf(a.y); oa.z = f2bf(a.z); oa.w = f2bf(a.w);
    oc.x = f2bf(c.x); oc.y = f2bf(c.y); oc.z = f2bf(c.z); oc.w = f2bf(c.w);
    *(short4*)&X[(size_t)r * K1_ + t * 4] = oa;
    *(short4*)&X[(size_t)r * K1_ + H_ + t * 4] = oc;
}

// ---------------------------------------------------------------------------
// 4) MFMA bf16 GEMM: C[M,N] = act(A[M,K] @ Wt[N,K]^T + bias)
//    64x64 tile, BK=64, 4 waves (each wave: 16 rows x 64 cols),
//    XOR-swizzled LDS (conflict-free b128 staging writes + frag reads).
// ---------------------------------------------------------------------------
__device__ __forceinline__ short* lds_ptr(short* base, int row, int byteoff) {
    return (short*)((char*)base + row * 128 + (byteoff ^ ((row & 7) << 4)));
}

template <int ACT>
__global__ __launch_bounds__(256) void gemm_mfma(
    const short* __restrict__ A,   // [M][K] bf16
    const short* __restrict__ Bt,  // [N][K] bf16
    const float* __restrict__ bias,
    short* __restrict__ C,         // [M][N] bf16
    int M, int N, int K) {
    __shared__ short As[64 * 64];
    __shared__ short Bs[64 * 64];

    const int tid = threadIdx.x;
    const int lane = tid & 63;
    const int wave = tid >> 6;
    const int llo = lane & 15;
    const int lhi = lane >> 4;
    const int m0 = wave * 16;
    const int row0 = blockIdx.y * 64;
    const int col0 = blockIdx.x * 64;

    f32x4 acc[4] = {{0, 0, 0, 0}, {0, 0, 0, 0}, {0, 0, 0, 0}, {0, 0, 0, 0}};

    for (int k0 = 0; k0 < K; k0 += 64) {
        // stage A tile (64 rows x 64 k) and B tile (64 cols x 64 k)
#pragma unroll
        for (int p = 0; p < 2; ++p) {
            int c = tid + p * 256;
            int r = c >> 3, j = c & 7;
            s16x8 va = *(const s16x8*)(A + (size_t)(row0 + r) * K + k0 + j * 8);
            *(s16x8*)lds_ptr(As, r, j * 16) = va;
            s16x8 vb = *(const s16x8*)(Bt + (size_t)(col0 + r) * K + k0 + j * 8);
            *(s16x8*)lds_ptr(Bs, r, j * 16) = vb;
        }
        __syncthreads();

#pragma unroll
        for (int ks = 0; ks < 2; ++ks) {
            s16x8 a = *(const s16x8*)lds_ptr(As, m0 + llo, ks * 64 + lhi * 16);
#pragma unroll
            for (int nf = 0; nf < 4; ++nf) {
                s16x8 b = *(const s16x8*)lds_ptr(Bs, nf * 16 + llo, ks * 64 + lhi * 16);
                acc[nf] = __builtin_amdgcn_mfma_f32_16x16x32_bf16(a, b, acc[nf], 0, 0, 0);
            }
        }
        __syncthreads();
    }

    // epilogue: D row=(lane>>4)*4+j, col=lane&15 (per m89)
#pragma unroll
    for (int nf = 0; nf < 4; ++nf) {
        int cc = col0 + nf * 16 + llo;
        float bv = bias[cc];
#pragma unroll
        for (int j = 0; j < 4; ++j) {
            int rr = row0 + m0 + lhi * 4 + j;
            float v = acc[nf][j] + bv;
            if (ACT) v = gelu_exact(v);
            C[(size_t)rr * N + cc] = f2bf(v);
        }
    }
}

// ---------------------------------------------------------------------------
// 5) gate[r] = sigmoid(dot(g1[r,:], Wg2) + bg2)   (g1 bf16)
// ---------------------------------------------------------------------------
__global__ __launch_bounds__(256) void gate_kernel(const short* __restrict__ g1,
                                                   const float* __restrict__ Wg2,
                                                   const float* __restrict__ bg2,
                                                   float* __restrict__ gate) {
    int r = blockIdx.x;
    const short* row = g1 + (size_t)r * H_;
    float s = 0.f;
    for (int k = threadIdx.x; k < H_; k += 256) s += bf2f(row[k]) * Wg2[k];
#pragma unroll
    for (int off = 32; off > 0; off >>= 1) s += __shfl_down(s, off);
    __shared__ float red[4];
    int lane = threadIdx.x & 63;
    int w = threadIdx.x >> 6;
    if (lane == 0) red[w] = s;
    __syncthreads();
    if (threadIdx.x == 0) {
        float t = red[0] + red[1] + red[2] + red[3] + bg2[0];
        gate[r] = 1.f / (1.f + expf(-t));
    }
}

// ---------------------------------------------------------------------------
// 6) scatter: out[b, idxc, :] = orig*(1-g) + iv*g  (last-write-wins over i)
// ---------------------------------------------------------------------------
__global__ __launch_bounds__(256) void scatter_kernel(const float* __restrict__ vs,
                                                      const float* __restrict__ iv,
                                                      const int* __restrict__ idx,
                                                      const float* __restrict__ gate,
                                                      float* __restrict__ out) {
    int blk = blockIdx.x;  // 0 .. B*NI-1
    int b = blk / NI_;
    int i = blk - b * NI_;
    int myid = idx[b * NI_ + i];
    bool valid = (myid >= 0) && (myid < V_);
    if (!valid) return;
    for (int j = i + 1; j < NI_; ++j) {
        int oid = idx[b * NI_ + j];
        if (oid >= 0 && oid < V_ && oid == myid) return;
    }
    float g = gate[blk];
    const float* orig = vs + (size_t)b * V_ * H_ + (size_t)myid * H_;
    const float* ivr = iv + (size_t)b * NI_ * H_ + (size_t)i * H_;
    float* dst = out + (size_t)b * V_ * H_ + (size_t)myid * H_;
    for (int h = threadIdx.x; h < H_; h += 256) {
        dst[h] = orig[h] * (1.f - g) + ivr[h] * g;
    }
}

// ---------------------------------------------------------------------------
extern "C" void kernel_launch(void* const* d_in, const int* in_sizes, int n_in,
                              void* d_out, int out_size, void* d_ws, size_t ws_size,
                              hipStream_t stream) {
    const float* vs  = (const float*)d_in[0];
    const float* iv  = (const float*)d_in[2];
    const float* W1  = (const float*)d_in[3];
    const float* b1  = (const float*)d_in[4];
    const float* W2  = (const float*)d_in[5];
    const float* b2  = (const float*)d_in[6];
    const float* Wg1 = (const float*)d_in[7];
    const float* bg1 = (const float*)d_in[8];
    const float* Wg2 = (const float*)d_in[9];
    const float* bg2 = (const float*)d_in[10];
    const int*   idx = (const int*)d_in[11];
    float* out = (float*)d_out;

    // workspace layout (bytes):
    // region A: X bf16 [M][1536] (12.58MB); enc bf16 [M][768] aliases it later
    // region B: h1 bf16 [M][768] (6.29MB); g1 bf16 aliases it later
    // gate fp32 [M]; W1t bf16 [768][1536]; W2t bf16 [768][768]; Wg1t bf16 [768][768]
    char* ws = (char*)d_ws;
    short* Xb   = (short*)ws;                                    // 12,582,912 B
    short* encb = Xb;                                            // alias (X dead)
    short* h1b  = (short*)(ws + (size_t)M_ * K1_ * 2);           // 6,291,456 B
    short* g1b  = h1b;                                           // alias (h1 dead)
    float* gate = (float*)(ws + (size_t)M_ * K1_ * 2 + (size_t)M_ * H_ * 2);
    short* W1t  = (short*)((char*)gate + M_ * 4);
    short* W2t  = W1t + (size_t)H_ * K1_;
    short* Wg1t = W2t + (size_t)H_ * H_;

    // 1) copy states to out
    int n4 = (B_ * V_ * H_) / 4;
    copy_kernel<<<2048, 256, 0, stream>>>((const float4*)vs, (float4*)out, n4);

    // 2) weight convert+transpose
    convert_transpose<<<dim3(H_ / 64, K1_ / 64), 256, 0, stream>>>(W1, W1t, K1_, H_);
    convert_transpose<<<dim3(H_ / 64, H_ / 64), 256, 0, stream>>>(W2, W2t, H_, H_);
    convert_transpose<<<dim3(H_ / 64, H_ / 64), 256, 0, stream>>>(Wg1, Wg1t, H_, H_);

    // 3) gather X
    gather_x<<<M_, 192, 0, stream>>>(vs, iv, idx, Xb);

    dim3 grid(H_ / 64, M_ / 64);  // (12, 64)
    // 4) h1 = gelu(X @ W1 + b1)      K=1536
    gemm_mfma<1><<<grid, 256, 0, stream>>>(Xb, W1t, b1, h1b, M_, H_, K1_);
    // 5) enc = h1 @ W2 + b2          K=768
    gemm_mfma<0><<<grid, 256, 0, stream>>>(h1b, W2t, b2, encb, M_, H_, H_);
    // 6) g1 = gelu(enc @ Wg1 + bg1)  K=768
    gemm_mfma<1><<<grid, 256, 0, stream>>>(encb, Wg1t, bg1, g1b, M_, H_, H_);
    // 7) gate = sigmoid(g1 @ Wg2 + bg2)
    gate_kernel<<<M_, 256, 0, stream>>>(g1b, Wg2, bg2, gate);
    // 8) scatter blended rows into out
    scatter_kernel<<<M_, 256, 0, stream>>>(vs, iv, idx, gate, out);
}

// Round 3
// 107.799 us; speedup vs baseline: 3.7103x; 1.3421x over previous
//
#include <hip/hip_runtime.h>
#include <math.h>

// Problem constants (B, V, H, NI, E) = (512, 50, 768, 8, 2)
#define B_  512
#define V_  50
#define H_  768
#define NI_ 8
#define M_  (B_ * NI_)   // 4096 MLP rows
#define K1_ (2 * H_)     // 1536
#define NCB_ 12          // gate partial column-blocks (768/64)

using f32x4 = __attribute__((ext_vector_type(4))) float;
using s16x8 = __attribute__((ext_vector_type(8))) short;

__device__ __forceinline__ float gelu_exact(float x) {
    return 0.5f * x * (1.0f + erff(x * 0.7071067811865476f));
}

__device__ __forceinline__ short f2bf(float f) {
    union { float f; unsigned u; } v; v.f = f;
    unsigned r = (v.u + 0x7fffu + ((v.u >> 16) & 1u)) >> 16;  // RNE
    return (short)r;
}

#define GLOAD16(g, l)                                                          \
    __builtin_amdgcn_global_load_lds(                                          \
        (const __attribute__((address_space(1))) void*)(g),                    \
        (__attribute__((address_space(3))) void*)(l), 16, 0, 0)

// ---------------------------------------------------------------------------
// 1) merged weight convert+transpose: fp32 W[K][N] -> bf16 Wt[N][K]
//    blocks 0..287: W1 (K=1536), 288..431: W2, 432..575: Wg1
// ---------------------------------------------------------------------------
__global__ __launch_bounds__(256) void convert_all(
    const float* __restrict__ W1, const float* __restrict__ W2,
    const float* __restrict__ Wg1, short* __restrict__ W1t,
    short* __restrict__ W2t, short* __restrict__ Wg1t) {
    __shared__ short s[64][65];
    int blk = blockIdx.x;
    const float* src; short* dst; int K, t;
    if (blk < 288)      { src = W1;  dst = W1t;  K = K1_; t = blk; }
    else if (blk < 432) { src = W2;  dst = W2t;  K = H_;  t = blk - 288; }
    else                { src = Wg1; dst = Wg1t; K = H_;  t = blk - 432; }
    int bx = t % 12, by = t / 12;
    int k0 = by * 64, n0 = bx * 64;
    int tid = threadIdx.x;
#pragma unroll
    for (int e = 0; e < 16; ++e) {
        int li = tid + e * 256;
        int kk = li >> 6, nn = li & 63;
        s[kk][nn] = f2bf(src[(size_t)(k0 + kk) * H_ + n0 + nn]);
    }
    __syncthreads();
#pragma unroll
    for (int e = 0; e < 16; ++e) {
        int li = tid + e * 256;
        int nn = li >> 6, kk = li & 63;
        dst[(size_t)(n0 + nn) * K + k0 + kk] = s[kk][nn];
    }
}

// ---------------------------------------------------------------------------
// 2) gather X[r][0:768]=vs[b,idxc], X[r][768:1536]=iv[b,i]  (bf16)
// ---------------------------------------------------------------------------
__global__ __launch_bounds__(192) void gather_x(const float* __restrict__ vs,
                                                const float* __restrict__ iv,
                                                const int* __restrict__ idx,
                                                short* __restrict__ X) {
    int r = blockIdx.x;              // 0..4095
    int b = r >> 3;
    int id = idx[r];
    id = min(max(id, 0), V_ - 1);
    const float4* s1 = (const float4*)(vs + ((size_t)b * V_ + id) * H_);
    const float4* s2 = (const float4*)(iv + (size_t)r * H_);
    int t = threadIdx.x;             // 0..191
    float4 a = s1[t];
    float4 c = s2[t];
    short4 oa, oc;
    oa.x = f2bf(a.x); oa.y = f2bf(a.y); oa.z = f2bf(a.z); oa.w = f2bf(a.w);
    oc.x = f2bf(c.x); oc.y = f2bf(c.y); oc.z = f2bf(c.z); oc.w = f2bf(c.w);
    *(short4*)&X[(size_t)r * K1_ + t * 4] = oa;
    *(short4*)&X[(size_t)r * K1_ + H_ + t * 4] = oc;
}

// ---------------------------------------------------------------------------
// 3) winner table: winner[b*V+v] = last valid i with idx[b,i]==v, else -1
// ---------------------------------------------------------------------------
__global__ __launch_bounds__(256) void prep_kernel(const int* __restrict__ idx,
                                                   int* __restrict__ winner) {
    int b = blockIdx.x * 256 + threadIdx.x;
    if (b >= B_) return;
    int id[NI_];
#pragma unroll
    for (int i = 0; i < NI_; ++i) id[i] = idx[b * NI_ + i];
    for (int v = 0; v < V_; ++v) {
        int wv = -1;
#pragma unroll
        for (int i = 0; i < NI_; ++i)
            if (id[i] == v) wv = i;  // v in [0,V) => implies valid
        winner[b * V_ + v] = wv;
    }
}

// ---------------------------------------------------------------------------
// 4) MFMA bf16 GEMM: C[M,N] = act(A[M,K] @ Bt[N,K]^T + bias)
//    BM=128, BN=64, BK=64, 4 waves each 32 rows x 64 cols.
//    global_load_lds w16 staging, pre-swizzled source <-> XOR-swizzled reads.
//    GATE=1: no C write; emit gate partials Σ gelu(.)·Wg2 per 64-col block.
// ---------------------------------------------------------------------------
__device__ __forceinline__ short* lds_ptr(short* base, int row, int byteoff) {
    return (short*)((char*)base + row * 128 + (byteoff ^ ((row & 7) << 4)));
}

template <int ACT, int GATE>
__global__ __launch_bounds__(256) void gemm_mfma(
    const short* __restrict__ A,   // [M][K] bf16
    const short* __restrict__ Bt,  // [N][K] bf16
    const float* __restrict__ bias,
    short* __restrict__ C,         // [M][N] bf16 (GATE=0)
    int M, int N, int K,
    const float* __restrict__ wg2, float* __restrict__ gate_part) {
    __shared__ short As[128 * 64];   // 16KB, 16 chunks of 1KB
    __shared__ short Bs[64 * 64];    // 8KB, 8 chunks

    const int tid = threadIdx.x;
    const int lane = tid & 63;
    const int wave = tid >> 6;
    const int llo = lane & 15;
    const int lhi = lane >> 4;
    const int row0 = blockIdx.y * 128;
    const int col0 = blockIdx.x * 64;

    // staging: 24 chunks of 1KB (8 rows each); wave w owns chunks w*6..w*6+5.
    // linear LDS pos (r, jj) must hold global chunk j = jj ^ (r&7).
    const short* gsrc[6];
    short* ldst[6];
#pragma unroll
    for (int p = 0; p < 6; ++p) {
        int c = wave * 6 + p;
        int jj = lane & 7;
        if (c < 16) {
            int r = c * 8 + (lane >> 3);
            int j = jj ^ (r & 7);
            gsrc[p] = A + (size_t)(row0 + r) * K + j * 8;
            ldst[p] = As + c * 512;
        } else {
            int r = (c - 16) * 8 + (lane >> 3);
            int j = jj ^ (r & 7);
            gsrc[p] = Bt + (size_t)(col0 + r) * K + j * 8;
            ldst[p] = Bs + (c - 16) * 512;
        }
    }

    f32x4 acc[2][4];
#pragma unroll
    for (int mi = 0; mi < 2; ++mi)
#pragma unroll
        for (int nf = 0; nf < 4; ++nf) acc[mi][nf] = (f32x4){0, 0, 0, 0};

    for (int k0 = 0; k0 < K; k0 += 64) {
#pragma unroll
        for (int p = 0; p < 6; ++p) {
            GLOAD16(gsrc[p], ldst[p]);
            gsrc[p] += 64;
        }
        __syncthreads();

#pragma unroll
        for (int ks = 0; ks < 2; ++ks) {
            s16x8 a[2], b[4];
#pragma unroll
            for (int mi = 0; mi < 2; ++mi)
                a[mi] = *(const s16x8*)lds_ptr(As, wave * 32 + mi * 16 + llo,
                                               ks * 64 + lhi * 16);
#pragma unroll
            for (int nf = 0; nf < 4; ++nf)
                b[nf] = *(const s16x8*)lds_ptr(Bs, nf * 16 + llo,
                                               ks * 64 + lhi * 16);
#pragma unroll
            for (int mi = 0; mi < 2; ++mi)
#pragma unroll
                for (int nf = 0; nf < 4; ++nf)
                    acc[mi][nf] = __builtin_amdgcn_mfma_f32_16x16x32_bf16(
                        a[mi], b[nf], acc[mi][nf], 0, 0, 0);
        }
        __syncthreads();
    }

    if (!GATE) {
        // C/D layout: col=lane&15, row=(lane>>4)*4+j
#pragma unroll
        for (int nf = 0; nf < 4; ++nf) {
            int cc = col0 + nf * 16 + llo;
            float bv = bias[cc];
#pragma unroll
            for (int mi = 0; mi < 2; ++mi) {
#pragma unroll
                for (int j = 0; j < 4; ++j) {
                    int rr = row0 + wave * 32 + mi * 16 + lhi * 4 + j;
                    float v = acc[mi][nf][j] + bv;
                    if (ACT) v = gelu_exact(v);
                    C[(size_t)rr * N + cc] = f2bf(v);
                }
            }
        }
    } else {
        // gate partials: s[mi][j] = Σ_nf gelu(acc+b)·wg2, reduce over llo
        float s[2][4];
#pragma unroll
        for (int mi = 0; mi < 2; ++mi)
#pragma unroll
            for (int j = 0; j < 4; ++j) s[mi][j] = 0.f;
#pragma unroll
        for (int nf = 0; nf < 4; ++nf) {
            int cc = col0 + nf * 16 + llo;
            float bv = bias[cc];
            float wv = wg2[cc];
#pragma unroll
            for (int mi = 0; mi < 2; ++mi)
#pragma unroll
                for (int j = 0; j < 4; ++j)
                    s[mi][j] += gelu_exact(acc[mi][nf][j] + bv) * wv;
        }
#pragma unroll
        for (int off = 1; off < 16; off <<= 1)
#pragma unroll
            for (int mi = 0; mi < 2; ++mi)
#pragma unroll
                for (int j = 0; j < 4; ++j)
                    s[mi][j] += __shfl_xor(s[mi][j], off);
        if (llo == 0) {
#pragma unroll
            for (int mi = 0; mi < 2; ++mi)
#pragma unroll
                for (int j = 0; j < 4; ++j) {
                    int rr = row0 + wave * 32 + mi * 16 + lhi * 4 + j;
                    gate_part[(size_t)rr * NCB_ + blockIdx.x] = s[mi][j];
                }
        }
    }
}

// ---------------------------------------------------------------------------
// 5) final write: out[b,v,:] = copy or blend (winner row), one row per block
// ---------------------------------------------------------------------------
__global__ __launch_bounds__(192) void final_write(
    const float* __restrict__ vs, const float* __restrict__ iv,
    const int* __restrict__ winner, const float* __restrict__ gate_part,
    const float* __restrict__ bg2, float* __restrict__ out) {
    int row = blockIdx.x;  // b*V + v
    int t = threadIdx.x;
    const float4* src = (const float4*)(vs + (size_t)row * H_);
    float4* dst = (float4*)(out + (size_t)row * H_);
    int w = winner[row];
    if (w < 0) {
        dst[t] = src[t];
        return;
    }
    int b = row / V_;
    int r = b * NI_ + w;
    __shared__ float gsh;
    if (t == 0) {
        float s = bg2[0];
#pragma unroll
        for (int c = 0; c < NCB_; ++c) s += gate_part[(size_t)r * NCB_ + c];
        gsh = 1.f / (1.f + expf(-s));
    }
    __syncthreads();
    float g = gsh;
    const float4* ivr = (const float4*)(iv + (size_t)r * H_);
    float4 o = src[t], x = ivr[t], res;
    res.x = o.x * (1.f - g) + x.x * g;
    res.y = o.y * (1.f - g) + x.y * g;
    res.z = o.z * (1.f - g) + x.z * g;
    res.w = o.w * (1.f - g) + x.w * g;
    dst[t] = res;
}

// ---------------------------------------------------------------------------
extern "C" void kernel_launch(void* const* d_in, const int* in_sizes, int n_in,
                              void* d_out, int out_size, void* d_ws, size_t ws_size,
                              hipStream_t stream) {
    const float* vs  = (const float*)d_in[0];
    const float* iv  = (const float*)d_in[2];
    const float* W1  = (const float*)d_in[3];
    const float* b1  = (const float*)d_in[4];
    const float* W2  = (const float*)d_in[5];
    const float* b2  = (const float*)d_in[6];
    const float* Wg1 = (const float*)d_in[7];
    const float* bg1 = (const float*)d_in[8];
    const float* Wg2 = (const float*)d_in[9];
    const float* bg2 = (const float*)d_in[10];
    const int*   idx = (const int*)d_in[11];
    float* out = (float*)d_out;

    // workspace layout
    char* ws = (char*)d_ws;
    short* Xb   = (short*)ws;                                  // 12.58 MB
    short* encb = Xb;                                          // alias (X dead after GEMM1... GEMM2 writes here)
    short* h1b  = (short*)(ws + (size_t)M_ * K1_ * 2);         // 6.29 MB
    float* gate_part = (float*)(ws + (size_t)M_ * K1_ * 2 + (size_t)M_ * H_ * 2);
    int*   winner = (int*)((char*)gate_part + (size_t)M_ * NCB_ * 4);
    short* W1t  = (short*)((char*)winner + (size_t)B_ * V_ * 4);
    short* W2t  = W1t + (size_t)H_ * K1_;
    short* Wg1t = W2t + (size_t)H_ * H_;

    // 1) weights -> bf16 transposed (one launch)
    convert_all<<<576, 256, 0, stream>>>(W1, W2, Wg1, W1t, W2t, Wg1t);
    // 2) gather X
    gather_x<<<M_, 192, 0, stream>>>(vs, iv, idx, Xb);
    // 3) winner table
    prep_kernel<<<2, 256, 0, stream>>>(idx, winner);

    dim3 grid(H_ / 64, M_ / 128);  // (12, 32) = 384 blocks for all GEMMs
    // 4) h1 = gelu(X @ W1 + b1)      K=1536
    gemm_mfma<1, 0><<<grid, 256, 0, stream>>>(Xb, W1t, b1, h1b, M_, H_, K1_, nullptr, nullptr);
    // 5) enc = h1 @ W2 + b2          K=768
    gemm_mfma<0, 0><<<grid, 256, 0, stream>>>(h1b, W2t, b2, encb, M_, H_, H_, nullptr, nullptr);
    // 6) gate partials from gelu(enc @ Wg1 + bg1) · Wg2  (no g1 materialization)
    gemm_mfma<1, 1><<<grid, 256, 0, stream>>>(encb, Wg1t, bg1, nullptr, M_, H_, H_, Wg2, gate_part);
    // 7) final: copy or blend each output row
    final_write<<<B_ * V_, 192, 0, stream>>>(vs, iv, winner, gate_part, bg2, out);
}

// Round 4
// 90.886 us; speedup vs baseline: 4.4008x; 1.1861x over previous
//
#include <hip/hip_runtime.h>
#include <math.h>

// Problem constants (B, V, H, NI, E) = (512, 50, 768, 8, 2)
#define B_  512
#define V_  50
#define H_  768
#define NI_ 8
#define M_  (B_ * NI_)   // 4096 MLP rows
#define K1_ (2 * H_)     // 1536
#define NCB_ 12          // gate partial column-blocks (768/64)

using f32x4 = __attribute__((ext_vector_type(4))) float;
using s16x8 = __attribute__((ext_vector_type(8))) short;

__device__ __forceinline__ float gelu_exact(float x) {
    return 0.5f * x * (1.0f + erff(x * 0.7071067811865476f));
}

__device__ __forceinline__ short f2bf(float f) {
    union { float f; unsigned u; } v; v.f = f;
    unsigned r = (v.u + 0x7fffu + ((v.u >> 16) & 1u)) >> 16;  // RNE
    return (short)r;
}

#define GLOAD16(g, l)                                                          \
    __builtin_amdgcn_global_load_lds(                                          \
        (const __attribute__((address_space(1))) void*)(g),                    \
        (__attribute__((address_space(3))) void*)(l), 16, 0, 0)

// ---------------------------------------------------------------------------
// 1) fused preprocessing:
//    blk <  576 : weight convert+transpose (W1 288 tiles, W2 144, Wg1 144)
//    blk < 1600 : gather X rows (4 rows/block)
//    else       : winner table (last valid i with idx[b,i]==v)
// ---------------------------------------------------------------------------
__global__ __launch_bounds__(256) void pre_kernel(
    const float* __restrict__ vs, const float* __restrict__ iv,
    const int* __restrict__ idx,
    const float* __restrict__ W1, const float* __restrict__ W2,
    const float* __restrict__ Wg1,
    short* __restrict__ W1t, short* __restrict__ W2t, short* __restrict__ Wg1t,
    short* __restrict__ X, int* __restrict__ winner) {
    __shared__ short s[64][65];
    const int blk = blockIdx.x;
    const int tid = threadIdx.x;

    if (blk < 576) {
        const float* src; short* dst; int K, t;
        if (blk < 288)      { src = W1;  dst = W1t;  K = K1_; t = blk; }
        else if (blk < 432) { src = W2;  dst = W2t;  K = H_;  t = blk - 288; }
        else                { src = Wg1; dst = Wg1t; K = H_;  t = blk - 432; }
        int bx = t % 12, by = t / 12;
        int k0 = by * 64, n0 = bx * 64;
#pragma unroll
        for (int e = 0; e < 16; ++e) {
            int li = tid + e * 256;
            int kk = li >> 6, nn = li & 63;
            s[kk][nn] = f2bf(src[(size_t)(k0 + kk) * H_ + n0 + nn]);
        }
        __syncthreads();
#pragma unroll
        for (int e = 0; e < 16; ++e) {
            int li = tid + e * 256;
            int nn = li >> 6, kk = li & 63;
            dst[(size_t)(n0 + nn) * K + k0 + kk] = s[kk][nn];
        }
    } else if (blk < 1600) {
        int g = blk - 576;                  // 0..1023
        int r = g * 4 + (tid >> 6);         // row 0..4095
        int lane = tid & 63;
        int b = r >> 3;
        int id = idx[r];
        id = min(max(id, 0), V_ - 1);
        const float4* s1 = (const float4*)(vs + ((size_t)b * V_ + id) * H_);
        const float4* s2 = (const float4*)(iv + (size_t)r * H_);
        short* xr = X + (size_t)r * K1_;
#pragma unroll
        for (int part = 0; part < 3; ++part) {
            int e = lane + part * 64;       // 0..191 float4 slots
            float4 a = s1[e];
            float4 c = s2[e];
            short4 oa, oc;
            oa.x = f2bf(a.x); oa.y = f2bf(a.y); oa.z = f2bf(a.z); oa.w = f2bf(a.w);
            oc.x = f2bf(c.x); oc.y = f2bf(c.y); oc.z = f2bf(c.z); oc.w = f2bf(c.w);
            *(short4*)&xr[e * 4] = oa;
            *(short4*)&xr[H_ + e * 4] = oc;
        }
    } else {
        int b = (blk - 1600) * 256 + tid;
        if (b < B_) {
            int id[NI_];
#pragma unroll
            for (int i = 0; i < NI_; ++i) id[i] = idx[b * NI_ + i];
            for (int v = 0; v < V_; ++v) {
                int wv = -1;
#pragma unroll
                for (int i = 0; i < NI_; ++i)
                    if (id[i] == v) wv = i;
                winner[b * V_ + v] = wv;
            }
        }
    }
}

// ---------------------------------------------------------------------------
// 2) MFMA bf16 GEMM: C[M,N] = act(A[M,K] @ Bt[N,K]^T + bias)
//    BM=128, BN=64, BK=64, 4 waves each 32 rows x 64 cols.
//    Double-buffered global_load_lds w16 prefetch, one barrier per K-step.
//    Pre-swizzled global source <-> XOR-swizzled ds_read (rule #21).
//    XCD-aware block swizzle (nwg=384, %8==0).
//    GATE=1: no C write; emit gate partials per 64-col block.
// ---------------------------------------------------------------------------
__device__ __forceinline__ short* lds_ptr(short* base, int row, int byteoff) {
    return (short*)((char*)base + row * 128 + (byteoff ^ ((row & 7) << 4)));
}

template <int ACT, int GATE>
__global__ __launch_bounds__(256) void gemm_mfma(
    const short* __restrict__ A,   // [M][K] bf16
    const short* __restrict__ Bt,  // [N][K] bf16
    const float* __restrict__ bias,
    short* __restrict__ C,         // [M][N] bf16 (GATE=0)
    int M, int N, int K,
    const float* __restrict__ wg2, float* __restrict__ gate_part) {
    __shared__ short As[2][128 * 64];  // 2 x 16KB
    __shared__ short Bs[2][64 * 64];   // 2 x 8KB

    const int tid = threadIdx.x;
    const int lane = tid & 63;
    const int wave = tid >> 6;
    const int llo = lane & 15;
    const int lhi = lane >> 4;

    // XCD swizzle: group 12 col-blocks of a row-panel on one XCD
    int f = blockIdx.y * gridDim.x + blockIdx.x;   // 0..383
    int sw = (f & 7) * 48 + (f >> 3);
    int bx = sw % 12, by = sw / 12;
    const int row0 = by * 128;
    const int col0 = bx * 64;

    // staging: 24 chunks of 1KB (A:16, B:8); wave w owns chunks w*6..w*6+5.
    // linear LDS chunk pos (r, jj) holds global j = jj ^ (r&7)  (inverse swz)
    const short* gsrc[6];
    short* ldst0[6];
    int lstep[6];
#pragma unroll
    for (int p = 0; p < 6; ++p) {
        int c = wave * 6 + p;
        int jj = lane & 7;
        if (c < 16) {
            int r = c * 8 + (lane >> 3);
            int j = jj ^ (r & 7);
            gsrc[p] = A + (size_t)(row0 + r) * K + j * 8;
            ldst0[p] = &As[0][c * 512];
            lstep[p] = 128 * 64;
        } else {
            int r = (c - 16) * 8 + (lane >> 3);
            int j = jj ^ (r & 7);
            gsrc[p] = Bt + (size_t)(col0 + r) * K + j * 8;
            ldst0[p] = &Bs[0][(c - 16) * 512];
            lstep[p] = 64 * 64;
        }
    }

    f32x4 acc[2][4];
#pragma unroll
    for (int mi = 0; mi < 2; ++mi)
#pragma unroll
        for (int nf = 0; nf < 4; ++nf) acc[mi][nf] = (f32x4){0, 0, 0, 0};

    const int nt = K >> 6;
    // prologue: stage tile 0 into buf 0
#pragma unroll
    for (int p = 0; p < 6; ++p) GLOAD16(gsrc[p], ldst0[p]);
    __syncthreads();

    for (int t = 0; t < nt; ++t) {
        const int cur = t & 1;
        if (t + 1 < nt) {
#pragma unroll
            for (int p = 0; p < 6; ++p)
                GLOAD16(gsrc[p] + (size_t)(t + 1) * 64,
                        ldst0[p] + (cur ^ 1) * lstep[p]);
        }
        short* Ab = (short*)As[cur];
        short* Bb = (short*)Bs[cur];
#pragma unroll
        for (int ks = 0; ks < 2; ++ks) {
            s16x8 a[2], b[4];
#pragma unroll
            for (int mi = 0; mi < 2; ++mi)
                a[mi] = *(const s16x8*)lds_ptr(Ab, wave * 32 + mi * 16 + llo,
                                               ks * 64 + lhi * 16);
#pragma unroll
            for (int nf = 0; nf < 4; ++nf)
                b[nf] = *(const s16x8*)lds_ptr(Bb, nf * 16 + llo,
                                               ks * 64 + lhi * 16);
#pragma unroll
            for (int mi = 0; mi < 2; ++mi)
#pragma unroll
                for (int nf = 0; nf < 4; ++nf)
                    acc[mi][nf] = __builtin_amdgcn_mfma_f32_16x16x32_bf16(
                        a[mi], b[nf], acc[mi][nf], 0, 0, 0);
        }
        __syncthreads();  // drains vmcnt (stage t+1 done) + lgkm; buffers safe
    }

    if (!GATE) {
        // C/D layout: col=lane&15, row=(lane>>4)*4+j
#pragma unroll
        for (int nf = 0; nf < 4; ++nf) {
            int cc = col0 + nf * 16 + llo;
            float bv = bias[cc];
#pragma unroll
            for (int mi = 0; mi < 2; ++mi) {
#pragma unroll
                for (int j = 0; j < 4; ++j) {
                    int rr = row0 + wave * 32 + mi * 16 + lhi * 4 + j;
                    float v = acc[mi][nf][j] + bv;
                    if (ACT) v = gelu_exact(v);
                    C[(size_t)rr * N + cc] = f2bf(v);
                }
            }
        }
    } else {
        float s[2][4];
#pragma unroll
        for (int mi = 0; mi < 2; ++mi)
#pragma unroll
            for (int j = 0; j < 4; ++j) s[mi][j] = 0.f;
#pragma unroll
        for (int nf = 0; nf < 4; ++nf) {
            int cc = col0 + nf * 16 + llo;
            float bv = bias[cc];
            float wv = wg2[cc];
#pragma unroll
            for (int mi = 0; mi < 2; ++mi)
#pragma unroll
                for (int j = 0; j < 4; ++j)
                    s[mi][j] += gelu_exact(acc[mi][nf][j] + bv) * wv;
        }
#pragma unroll
        for (int off = 1; off < 16; off <<= 1)
#pragma unroll
            for (int mi = 0; mi < 2; ++mi)
#pragma unroll
                for (int j = 0; j < 4; ++j)
                    s[mi][j] += __shfl_xor(s[mi][j], off);
        if (llo == 0) {
#pragma unroll
            for (int mi = 0; mi < 2; ++mi)
#pragma unroll
                for (int j = 0; j < 4; ++j) {
                    int rr = row0 + wave * 32 + mi * 16 + lhi * 4 + j;
                    gate_part[(size_t)rr * NCB_ + bx] = s[mi][j];
                }
        }
    }
}

// ---------------------------------------------------------------------------
// 3) final write: out[b,v,:] = copy or blend (winner row), one row per block
// ---------------------------------------------------------------------------
__global__ __launch_bounds__(192) void final_write(
    const float* __restrict__ vs, const float* __restrict__ iv,
    const int* __restrict__ winner, const float* __restrict__ gate_part,
    const float* __restrict__ bg2, float* __restrict__ out) {
    int row = blockIdx.x;  // b*V + v
    int t = threadIdx.x;
    const float4* src = (const float4*)(vs + (size_t)row * H_);
    float4* dst = (float4*)(out + (size_t)row * H_);
    int w = winner[row];
    if (w < 0) {
        dst[t] = src[t];
        return;
    }
    int b = row / V_;
    int r = b * NI_ + w;
    __shared__ float gsh;
    if (t == 0) {
        float s = bg2[0];
#pragma unroll
        for (int c = 0; c < NCB_; ++c) s += gate_part[(size_t)r * NCB_ + c];
        gsh = 1.f / (1.f + expf(-s));
    }
    __syncthreads();
    float g = gsh;
    const float4* ivr = (const float4*)(iv + (size_t)r * H_);
    float4 o = src[t], x = ivr[t], res;
    res.x = o.x * (1.f - g) + x.x * g;
    res.y = o.y * (1.f - g) + x.y * g;
    res.z = o.z * (1.f - g) + x.z * g;
    res.w = o.w * (1.f - g) + x.w * g;
    dst[t] = res;
}

// ---------------------------------------------------------------------------
extern "C" void kernel_launch(void* const* d_in, const int* in_sizes, int n_in,
                              void* d_out, int out_size, void* d_ws, size_t ws_size,
                              hipStream_t stream) {
    const float* vs  = (const float*)d_in[0];
    const float* iv  = (const float*)d_in[2];
    const float* W1  = (const float*)d_in[3];
    const float* b1  = (const float*)d_in[4];
    const float* W2  = (const float*)d_in[5];
    const float* b2  = (const float*)d_in[6];
    const float* Wg1 = (const float*)d_in[7];
    const float* bg1 = (const float*)d_in[8];
    const float* Wg2 = (const float*)d_in[9];
    const float* bg2 = (const float*)d_in[10];
    const int*   idx = (const int*)d_in[11];
    float* out = (float*)d_out;

    // workspace layout
    char* ws = (char*)d_ws;
    short* Xb   = (short*)ws;                                  // 12.58 MB
    short* encb = Xb;                                          // alias (X dead after GEMM1)
    short* h1b  = (short*)(ws + (size_t)M_ * K1_ * 2);         // 6.29 MB
    float* gate_part = (float*)(ws + (size_t)M_ * K1_ * 2 + (size_t)M_ * H_ * 2);
    int*   winner = (int*)((char*)gate_part + (size_t)M_ * NCB_ * 4);
    short* W1t  = (short*)((char*)winner + (size_t)B_ * V_ * 4);
    short* W2t  = W1t + (size_t)H_ * K1_;
    short* Wg1t = W2t + (size_t)H_ * H_;

    // 1) fused preprocessing (converts + gather + winner table)
    pre_kernel<<<1602, 256, 0, stream>>>(vs, iv, idx, W1, W2, Wg1,
                                         W1t, W2t, Wg1t, Xb, winner);

    dim3 grid(H_ / 64, M_ / 128);  // (12, 32) = 384 blocks
    // 2) h1 = gelu(X @ W1 + b1)      K=1536
    gemm_mfma<1, 0><<<grid, 256, 0, stream>>>(Xb, W1t, b1, h1b, M_, H_, K1_, nullptr, nullptr);
    // 3) enc = h1 @ W2 + b2          K=768
    gemm_mfma<0, 0><<<grid, 256, 0, stream>>>(h1b, W2t, b2, encb, M_, H_, H_, nullptr, nullptr);
    // 4) gate partials from gelu(enc @ Wg1 + bg1) · Wg2
    gemm_mfma<1, 1><<<grid, 256, 0, stream>>>(encb, Wg1t, bg1, nullptr, M_, H_, H_, Wg2, gate_part);
    // 5) final: copy or blend each output row
    final_write<<<B_ * V_, 192, 0, stream>>>(vs, iv, winner, gate_part, bg2, out);
}

// Round 5
// 81.357 us; speedup vs baseline: 4.9162x; 1.1171x over previous
//
#include <hip/hip_runtime.h>
#include <math.h>

// Problem constants (B, V, H, NI, E) = (512, 50, 768, 8, 2)
#define B_  512
#define V_  50
#define H_  768
#define NI_ 8
#define M_  (B_ * NI_)   // 4096 MLP rows
#define K1_ (2 * H_)     // 1536
#define NCB_ 12          // gate partial column-blocks (768/64)
#define NGEMM_ 384       // MFMA blocks per GEMM launch
#define NCOPY_ 256       // copy-overlay blocks per GEMM launch
#define COPY_PER_BLK_ 6400  // float4 per copy block (3*256*6400 = B*V*H/4)

using f32x4 = __attribute__((ext_vector_type(4))) float;
using s16x8 = __attribute__((ext_vector_type(8))) short;

__device__ __forceinline__ float gelu_exact(float x) {
    return 0.5f * x * (1.0f + erff(x * 0.7071067811865476f));
}

__device__ __forceinline__ short f2bf(float f) {
    union { float f; unsigned u; } v; v.f = f;
    unsigned r = (v.u + 0x7fffu + ((v.u >> 16) & 1u)) >> 16;  // RNE
    return (short)r;
}

#define GLOAD16(g, l)                                                          \
    __builtin_amdgcn_global_load_lds(                                          \
        (const __attribute__((address_space(1))) void*)(g),                    \
        (__attribute__((address_space(3))) void*)(l), 16, 0, 0)

// ---------------------------------------------------------------------------
// 1) fused preprocessing:
//    blk <  576 : weight convert+transpose (W1 288 tiles, W2 144, Wg1 144)
//    else       : gather X rows (4 rows/block)
// ---------------------------------------------------------------------------
__global__ __launch_bounds__(256) void pre_kernel(
    const float* __restrict__ vs, const float* __restrict__ iv,
    const int* __restrict__ idx,
    const float* __restrict__ W1, const float* __restrict__ W2,
    const float* __restrict__ Wg1,
    short* __restrict__ W1t, short* __restrict__ W2t, short* __restrict__ Wg1t,
    short* __restrict__ X) {
    __shared__ short s[64][65];
    const int blk = blockIdx.x;
    const int tid = threadIdx.x;

    if (blk < 576) {
        const float* src; short* dst; int K, t;
        if (blk < 288)      { src = W1;  dst = W1t;  K = K1_; t = blk; }
        else if (blk < 432) { src = W2;  dst = W2t;  K = H_;  t = blk - 288; }
        else                { src = Wg1; dst = Wg1t; K = H_;  t = blk - 432; }
        int bx = t % 12, by = t / 12;
        int k0 = by * 64, n0 = bx * 64;
#pragma unroll
        for (int e = 0; e < 16; ++e) {
            int li = tid + e * 256;
            int kk = li >> 6, nn = li & 63;
            s[kk][nn] = f2bf(src[(size_t)(k0 + kk) * H_ + n0 + nn]);
        }
        __syncthreads();
#pragma unroll
        for (int e = 0; e < 16; ++e) {
            int li = tid + e * 256;
            int nn = li >> 6, kk = li & 63;
            dst[(size_t)(n0 + nn) * K + k0 + kk] = s[kk][nn];
        }
    } else {
        int g = blk - 576;                  // 0..1023
        int r = g * 4 + (tid >> 6);         // row 0..4095
        int lane = tid & 63;
        int b = r >> 3;
        int id = idx[r];
        id = min(max(id, 0), V_ - 1);
        const float4* s1 = (const float4*)(vs + ((size_t)b * V_ + id) * H_);
        const float4* s2 = (const float4*)(iv + (size_t)r * H_);
        short* xr = X + (size_t)r * K1_;
#pragma unroll
        for (int part = 0; part < 3; ++part) {
            int e = lane + part * 64;       // 0..191 float4 slots
            float4 a = s1[e];
            float4 c = s2[e];
            short4 oa, oc;
            oa.x = f2bf(a.x); oa.y = f2bf(a.y); oa.z = f2bf(a.z); oa.w = f2bf(a.w);
            oc.x = f2bf(c.x); oc.y = f2bf(c.y); oc.z = f2bf(c.z); oc.w = f2bf(c.w);
            *(short4*)&xr[e * 4] = oa;
            *(short4*)&xr[H_ + e * 4] = oc;
        }
    }
}

// ---------------------------------------------------------------------------
// 2) MFMA bf16 GEMM + copy overlay.
//    blocks [0,384):  C[M,N] = act(A[M,K] @ Bt[N,K]^T + bias)
//      BM=128, BN=64, BK=64, 4 waves, dbuf global_load_lds w16 prefetch,
//      pre-swizzled source <-> XOR-swizzled ds_read, XCD-aware swizzle.
//      GATE=1: no C write; emit gate partials per 64-col block.
//    blocks [384,640): stream 1/3 of vs -> out (float4), hides under MFMA.
// ---------------------------------------------------------------------------
__device__ __forceinline__ short* lds_ptr(short* base, int row, int byteoff) {
    return (short*)((char*)base + row * 128 + (byteoff ^ ((row & 7) << 4)));
}

template <int ACT, int GATE>
__global__ __launch_bounds__(256) void gemm_mfma(
    const short* __restrict__ A,   // [M][K] bf16
    const short* __restrict__ Bt,  // [N][K] bf16
    const float* __restrict__ bias,
    short* __restrict__ C,         // [M][N] bf16 (GATE=0)
    int M, int N, int K,
    const float* __restrict__ wg2, float* __restrict__ gate_part,
    const float4* __restrict__ cpy_src, float4* __restrict__ cpy_dst,
    size_t cpy_base) {
    __shared__ short As[2][128 * 64];  // 2 x 16KB
    __shared__ short Bs[2][64 * 64];   // 2 x 8KB

    const int tid = threadIdx.x;
    const int bid = blockIdx.x;

    if (bid >= NGEMM_) {
        // ---- copy overlay path ----
        size_t base = cpy_base + (size_t)(bid - NGEMM_) * COPY_PER_BLK_;
#pragma unroll 5
        for (int e = 0; e < COPY_PER_BLK_ / 256; ++e) {
            size_t i = base + (size_t)e * 256 + tid;
            cpy_dst[i] = cpy_src[i];
        }
        return;
    }

    const int lane = tid & 63;
    const int wave = tid >> 6;
    const int llo = lane & 15;
    const int lhi = lane >> 4;

    // XCD swizzle: group 12 col-blocks of a row-panel on one XCD (384%8==0)
    int sw = (bid & 7) * 48 + (bid >> 3);
    int bx = sw % 12, by = sw / 12;
    const int row0 = by * 128;
    const int col0 = bx * 64;

    // staging: 24 chunks of 1KB (A:16, B:8); wave w owns chunks w*6..w*6+5.
    // linear LDS chunk pos (r, jj) holds global j = jj ^ (r&7)  (inverse swz)
    const short* gsrc[6];
    short* ldst0[6];
    int lstep[6];
#pragma unroll
    for (int p = 0; p < 6; ++p) {
        int c = wave * 6 + p;
        int jj = lane & 7;
        if (c < 16) {
            int r = c * 8 + (lane >> 3);
            int j = jj ^ (r & 7);
            gsrc[p] = A + (size_t)(row0 + r) * K + j * 8;
            ldst0[p] = &As[0][c * 512];
            lstep[p] = 128 * 64;
        } else {
            int r = (c - 16) * 8 + (lane >> 3);
            int j = jj ^ (r & 7);
            gsrc[p] = Bt + (size_t)(col0 + r) * K + j * 8;
            ldst0[p] = &Bs[0][(c - 16) * 512];
            lstep[p] = 64 * 64;
        }
    }

    f32x4 acc[2][4];
#pragma unroll
    for (int mi = 0; mi < 2; ++mi)
#pragma unroll
        for (int nf = 0; nf < 4; ++nf) acc[mi][nf] = (f32x4){0, 0, 0, 0};

    const int nt = K >> 6;
#pragma unroll
    for (int p = 0; p < 6; ++p) GLOAD16(gsrc[p], ldst0[p]);
    __syncthreads();

    for (int t = 0; t < nt; ++t) {
        const int cur = t & 1;
        if (t + 1 < nt) {
#pragma unroll
            for (int p = 0; p < 6; ++p)
                GLOAD16(gsrc[p] + (size_t)(t + 1) * 64,
                        ldst0[p] + (cur ^ 1) * lstep[p]);
        }
        short* Ab = (short*)As[cur];
        short* Bb = (short*)Bs[cur];
#pragma unroll
        for (int ks = 0; ks < 2; ++ks) {
            s16x8 a[2], b[4];
#pragma unroll
            for (int mi = 0; mi < 2; ++mi)
                a[mi] = *(const s16x8*)lds_ptr(Ab, wave * 32 + mi * 16 + llo,
                                               ks * 64 + lhi * 16);
#pragma unroll
            for (int nf = 0; nf < 4; ++nf)
                b[nf] = *(const s16x8*)lds_ptr(Bb, nf * 16 + llo,
                                               ks * 64 + lhi * 16);
#pragma unroll
            for (int mi = 0; mi < 2; ++mi)
#pragma unroll
                for (int nf = 0; nf < 4; ++nf)
                    acc[mi][nf] = __builtin_amdgcn_mfma_f32_16x16x32_bf16(
                        a[mi], b[nf], acc[mi][nf], 0, 0, 0);
        }
        __syncthreads();  // drains vmcnt (stage t+1 done) + lgkm
    }

    if (!GATE) {
        // C/D layout: col=lane&15, row=(lane>>4)*4+j
#pragma unroll
        for (int nf = 0; nf < 4; ++nf) {
            int cc = col0 + nf * 16 + llo;
            float bv = bias[cc];
#pragma unroll
            for (int mi = 0; mi < 2; ++mi) {
#pragma unroll
                for (int j = 0; j < 4; ++j) {
                    int rr = row0 + wave * 32 + mi * 16 + lhi * 4 + j;
                    float v = acc[mi][nf][j] + bv;
                    if (ACT) v = gelu_exact(v);
                    C[(size_t)rr * N + cc] = f2bf(v);
                }
            }
        }
    } else {
        float s[2][4];
#pragma unroll
        for (int mi = 0; mi < 2; ++mi)
#pragma unroll
            for (int j = 0; j < 4; ++j) s[mi][j] = 0.f;
#pragma unroll
        for (int nf = 0; nf < 4; ++nf) {
            int cc = col0 + nf * 16 + llo;
            float bv = bias[cc];
            float wv = wg2[cc];
#pragma unroll
            for (int mi = 0; mi < 2; ++mi)
#pragma unroll
                for (int j = 0; j < 4; ++j)
                    s[mi][j] += gelu_exact(acc[mi][nf][j] + bv) * wv;
        }
#pragma unroll
        for (int off = 1; off < 16; off <<= 1)
#pragma unroll
            for (int mi = 0; mi < 2; ++mi)
#pragma unroll
                for (int j = 0; j < 4; ++j)
                    s[mi][j] += __shfl_xor(s[mi][j], off);
        if (llo == 0) {
#pragma unroll
            for (int mi = 0; mi < 2; ++mi)
#pragma unroll
                for (int j = 0; j < 4; ++j) {
                    int rr = row0 + wave * 32 + mi * 16 + lhi * 4 + j;
                    gate_part[(size_t)rr * NCB_ + bx] = s[mi][j];
                }
        }
    }
}

// ---------------------------------------------------------------------------
// 3) final blend: winner rows only. Row r=(b,i) blends out[b,idx[r],:] iff
//    idx valid and no later j targets the same slot (last-write-wins).
// ---------------------------------------------------------------------------
__global__ __launch_bounds__(192) void final_blend(
    const float* __restrict__ vs, const float* __restrict__ iv,
    const int* __restrict__ idx, const float* __restrict__ gate_part,
    const float* __restrict__ bg2, float* __restrict__ out) {
    int r = blockIdx.x;  // b*NI + i
    int b = r >> 3, i = r & 7;
    int id = idx[r];
    if (id < 0 || id >= V_) return;
    for (int j = i + 1; j < NI_; ++j)
        if (idx[b * NI_ + j] == id) return;  // a later valid write wins
    __shared__ float gsh;
    if (threadIdx.x == 0) {
        float s = bg2[0];
#pragma unroll
        for (int c = 0; c < NCB_; ++c) s += gate_part[(size_t)r * NCB_ + c];
        gsh = 1.f / (1.f + expf(-s));
    }
    __syncthreads();
    float g = gsh;
    int t = threadIdx.x;
    const float4* src = (const float4*)(vs + ((size_t)b * V_ + id) * H_);
    const float4* ivr = (const float4*)(iv + (size_t)r * H_);
    float4* dst = (float4*)(out + ((size_t)b * V_ + id) * H_);
    float4 o = src[t], x = ivr[t], res;
    res.x = o.x * (1.f - g) + x.x * g;
    res.y = o.y * (1.f - g) + x.y * g;
    res.z = o.z * (1.f - g) + x.z * g;
    res.w = o.w * (1.f - g) + x.w * g;
    dst[t] = res;
}

// ---------------------------------------------------------------------------
extern "C" void kernel_launch(void* const* d_in, const int* in_sizes, int n_in,
                              void* d_out, int out_size, void* d_ws, size_t ws_size,
                              hipStream_t stream) {
    const float* vs  = (const float*)d_in[0];
    const float* iv  = (const float*)d_in[2];
    const float* W1  = (const float*)d_in[3];
    const float* b1  = (const float*)d_in[4];
    const float* W2  = (const float*)d_in[5];
    const float* b2  = (const float*)d_in[6];
    const float* Wg1 = (const float*)d_in[7];
    const float* bg1 = (const float*)d_in[8];
    const float* Wg2 = (const float*)d_in[9];
    const float* bg2 = (const float*)d_in[10];
    const int*   idx = (const int*)d_in[11];
    float* out = (float*)d_out;

    // workspace layout
    char* ws = (char*)d_ws;
    short* Xb   = (short*)ws;                                  // 12.58 MB
    short* encb = Xb;                                          // alias (X dead after GEMM1)
    short* h1b  = (short*)(ws + (size_t)M_ * K1_ * 2);         // 6.29 MB
    float* gate_part = (float*)(ws + (size_t)M_ * K1_ * 2 + (size_t)M_ * H_ * 2);
    short* W1t  = (short*)((char*)gate_part + (size_t)M_ * NCB_ * 4);
    short* W2t  = W1t + (size_t)H_ * K1_;
    short* Wg1t = W2t + (size_t)H_ * H_;

    const float4* cs = (const float4*)vs;
    float4* cd = (float4*)out;
    const size_t CHUNK = (size_t)NCOPY_ * COPY_PER_BLK_;  // 1,638,400 float4

    // 1) fused preprocessing (weight converts + gather)
    pre_kernel<<<1600, 256, 0, stream>>>(vs, iv, idx, W1, W2, Wg1,
                                         W1t, W2t, Wg1t, Xb);

    const int nblk = NGEMM_ + NCOPY_;  // 640
    // 2) h1 = gelu(X @ W1 + b1)      K=1536   (+ copy third 0)
    gemm_mfma<1, 0><<<nblk, 256, 0, stream>>>(Xb, W1t, b1, h1b, M_, H_, K1_,
                                              nullptr, nullptr, cs, cd, 0);
    // 3) enc = h1 @ W2 + b2          K=768    (+ copy third 1)
    gemm_mfma<0, 0><<<nblk, 256, 0, stream>>>(h1b, W2t, b2, encb, M_, H_, H_,
                                              nullptr, nullptr, cs, cd, CHUNK);
    // 4) gate partials               K=768    (+ copy third 2)
    gemm_mfma<1, 1><<<nblk, 256, 0, stream>>>(encb, Wg1t, bg1, nullptr, M_, H_, H_,
                                              Wg2, gate_part, cs, cd, 2 * CHUNK);
    // 5) blend winner rows
    final_blend<<<M_, 192, 0, stream>>>(vs, iv, idx, gate_part, bg2, out);
}

// Round 7
// 75.444 us; speedup vs baseline: 5.3015x; 1.0784x over previous
//
#include <hip/hip_runtime.h>
#include <math.h>

// Problem constants (B, V, H, NI, E) = (512, 50, 768, 8, 2)
#define B_  512
#define V_  50
#define H_  768
#define NI_ 8
#define M_  (B_ * NI_)   // 4096 MLP rows
#define K1_ (2 * H_)     // 1536
#define NCB_ 12          // gate partial column-blocks (768/64)
#define N4_     4915200  // B*V*H/4 float4 of the output
#define SPLIT4_ 2949120  // 60% copied during mega1, 40% during gate

using f32x4 = __attribute__((ext_vector_type(4))) float;
using s16x8 = __attribute__((ext_vector_type(8))) short;

__device__ __forceinline__ float gelu_exact(float x) {
    return 0.5f * x * (1.0f + erff(x * 0.7071067811865476f));
}

__device__ __forceinline__ short f2bf(float f) {
    union { float f; unsigned u; } v; v.f = f;
    unsigned r = (v.u + 0x7fffu + ((v.u >> 16) & 1u)) >> 16;  // RNE
    return (short)r;
}

#define GLOAD16(g, l)                                                          \
    __builtin_amdgcn_global_load_lds(                                          \
        (const __attribute__((address_space(1))) void*)(g),                    \
        (__attribute__((address_space(3))) void*)(l), 16, 0, 0)

__device__ __forceinline__ short* lds_ptr(short* base, int row, int byteoff) {
    return (short*)((char*)base + row * 128 + (byteoff ^ ((row & 7) << 4)));
}

// ---------------------------------------------------------------------------
// 1) fused preprocessing:
//    blk <  288 : W1 convert+transpose -> W1t [768][1536]
//    blk <  432 : W2 plain convert (row-major) -> W2b [768][768]
//    blk <  576 : Wg1 convert+transpose -> Wg1t [768][768]
//    blk < 1600 : gather X rows (4 rows/block)
//    else (12)  : bc[j] = bg1[j] + sum_k b2[k]*Wg1[k][j]
// ---------------------------------------------------------------------------
__global__ __launch_bounds__(256) void pre_kernel(
    const float* __restrict__ vs, const float* __restrict__ iv,
    const int* __restrict__ idx,
    const float* __restrict__ W1, const float* __restrict__ W2,
    const float* __restrict__ Wg1,
    const float* __restrict__ b2, const float* __restrict__ bg1,
    short* __restrict__ W1t, short* __restrict__ W2b, short* __restrict__ Wg1t,
    short* __restrict__ X, float* __restrict__ bc) {
    __shared__ short s[64][65];
    const int blk = blockIdx.x;
    const int tid = threadIdx.x;

    if (blk < 288 || (blk >= 432 && blk < 576)) {
        // convert + transpose
        const float* src; short* dst; int K, t;
        if (blk < 288) { src = W1;  dst = W1t;  K = K1_; t = blk; }
        else           { src = Wg1; dst = Wg1t; K = H_;  t = blk - 432; }
        int bx = t % 12, by = t / 12;
        int k0 = by * 64, n0 = bx * 64;
#pragma unroll
        for (int e = 0; e < 16; ++e) {
            int li = tid + e * 256;
            int kk = li >> 6, nn = li & 63;
            s[kk][nn] = f2bf(src[(size_t)(k0 + kk) * H_ + n0 + nn]);
        }
        __syncthreads();
#pragma unroll
        for (int e = 0; e < 16; ++e) {
            int li = tid + e * 256;
            int nn = li >> 6, kk = li & 63;
            dst[(size_t)(n0 + nn) * K + k0 + kk] = s[kk][nn];
        }
    } else if (blk < 432) {
        // plain convert W2 -> W2b (row-major bf16), 4096 elems/block
        size_t base = (size_t)(blk - 288) * 4096;
#pragma unroll
        for (int e = 0; e < 4; ++e) {
            size_t i = base + (size_t)e * 1024 + tid * 4;
            float4 a = *(const float4*)(W2 + i);
            short4 o;
            o.x = f2bf(a.x); o.y = f2bf(a.y); o.z = f2bf(a.z); o.w = f2bf(a.w);
            *(short4*)(W2b + i) = o;
        }
    } else if (blk < 1600) {
        int g = blk - 576;                  // 0..1023
        int r = g * 4 + (tid >> 6);         // row 0..4095
        int lane = tid & 63;
        int b = r >> 3;
        int id = idx[r];
        id = min(max(id, 0), V_ - 1);
        const float4* s1 = (const float4*)(vs + ((size_t)b * V_ + id) * H_);
        const float4* s2 = (const float4*)(iv + (size_t)r * H_);
        short* xr = X + (size_t)r * K1_;
#pragma unroll
        for (int part = 0; part < 3; ++part) {
            int e = lane + part * 64;       // 0..191 float4 slots
            float4 a = s1[e];
            float4 c = s2[e];
            short4 oa, oc;
            oa.x = f2bf(a.x); oa.y = f2bf(a.y); oa.z = f2bf(a.z); oa.w = f2bf(a.w);
            oc.x = f2bf(c.x); oc.y = f2bf(c.y); oc.z = f2bf(c.z); oc.w = f2bf(c.w);
            *(short4*)&xr[e * 4] = oa;
            *(short4*)&xr[H_ + e * 4] = oc;
        }
    } else {
        // bc: 12 blocks x 64 columns
        __shared__ float part[4][64];
        int c = blk - 1600;
        int sub = tid >> 6;     // k-chunk 0..3 (192 k each)
        int jj = tid & 63;
        int j = c * 64 + jj;
        float sum = 0.f;
        for (int k = sub * 192; k < sub * 192 + 192; ++k)
            sum += b2[k] * Wg1[(size_t)k * H_ + j];
        part[sub][jj] = sum;
        __syncthreads();
        if (sub == 0)
            bc[j] = part[0][jj] + part[1][jj] + part[2][jj] + part[3][jj] + bg1[j];
    }
}

// ---------------------------------------------------------------------------
// shared GEMM body: C[m][n] = act(sum_k A[m][k]*Bt[n][k] + bias[n]),
// BM=128 BN=64 BK=64, 4 waves, dbuf global_load_lds w16 prefetch,
// pre-swizzled src <-> XOR-swizzled ds_read (rule #21).
// ---------------------------------------------------------------------------
__device__ __forceinline__ void gemm_body(
    const short* __restrict__ A, const short* __restrict__ Bt,
    const float* __restrict__ bias, short* __restrict__ C,
    int N, int K, int act, int row0, int col0,
    short (*As)[128 * 64], short (*Bs)[64 * 64], int tid) {
    const int lane = tid & 63;
    const int wave = tid >> 6;
    const int llo = lane & 15;
    const int lhi = lane >> 4;

    const short* gsrc[6];
    short* ldst0[6];
    int lstep[6];
#pragma unroll
    for (int p = 0; p < 6; ++p) {
        int c = wave * 6 + p;
        int jj = lane & 7;
        if (c < 16) {
            int r = c * 8 + (lane >> 3);
            int j = jj ^ (r & 7);
            gsrc[p] = A + (size_t)(row0 + r) * K + j * 8;
            ldst0[p] = &As[0][c * 512];
            lstep[p] = 128 * 64;
        } else {
            int r = (c - 16) * 8 + (lane >> 3);
            int j = jj ^ (r & 7);
            gsrc[p] = Bt + (size_t)(col0 + r) * K + j * 8;
            ldst0[p] = &Bs[0][(c - 16) * 512];
            lstep[p] = 64 * 64;
        }
    }

    f32x4 acc[2][4];
#pragma unroll
    for (int mi = 0; mi < 2; ++mi)
#pragma unroll
        for (int nf = 0; nf < 4; ++nf) acc[mi][nf] = (f32x4){0, 0, 0, 0};

    const int nt = K >> 6;
#pragma unroll
    for (int p = 0; p < 6; ++p) GLOAD16(gsrc[p], ldst0[p]);
    __syncthreads();

    for (int t = 0; t < nt; ++t) {
        const int cur = t & 1;
        if (t + 1 < nt) {
#pragma unroll
            for (int p = 0; p < 6; ++p)
                GLOAD16(gsrc[p] + (size_t)(t + 1) * 64,
                        ldst0[p] + (cur ^ 1) * lstep[p]);
        }
        short* Ab = (short*)As[cur];
        short* Bb = (short*)Bs[cur];
#pragma unroll
        for (int ks = 0; ks < 2; ++ks) {
            s16x8 a[2], b[4];
#pragma unroll
            for (int mi = 0; mi < 2; ++mi)
                a[mi] = *(const s16x8*)lds_ptr(Ab, wave * 32 + mi * 16 + llo,
                                               ks * 64 + lhi * 16);
#pragma unroll
            for (int nf = 0; nf < 4; ++nf)
                b[nf] = *(const s16x8*)lds_ptr(Bb, nf * 16 + llo,
                                               ks * 64 + lhi * 16);
#pragma unroll
            for (int mi = 0; mi < 2; ++mi)
#pragma unroll
                for (int nf = 0; nf < 4; ++nf)
                    acc[mi][nf] = __builtin_amdgcn_mfma_f32_16x16x32_bf16(
                        a[mi], b[nf], acc[mi][nf], 0, 0, 0);
        }
        __syncthreads();
    }

    // C/D layout: col=lane&15, row=(lane>>4)*4+j
#pragma unroll
    for (int nf = 0; nf < 4; ++nf) {
        int cc = col0 + nf * 16 + llo;
        float bv = bias ? bias[cc] : 0.0f;
#pragma unroll
        for (int mi = 0; mi < 2; ++mi) {
#pragma unroll
            for (int j = 0; j < 4; ++j) {
                int rr = row0 + wave * 32 + mi * 16 + lhi * 4 + j;
                float v = acc[mi][nf][j] + bv;
                if (act) v = gelu_exact(v);
                C[(size_t)rr * N + cc] = f2bf(v);
            }
        }
    }
}

// ---------------------------------------------------------------------------
// 2) mega1: [0,384)  GEMM1 h1=gelu(X@W1t^T+b1)
//           [384,456) Wct[n][k] = sum_j Wg1t[n][j]*W2b[k][j]  (=(W2@Wg1)^T)
//           [456,640) copy overlay of out[0, SPLIT4)
// ---------------------------------------------------------------------------
__global__ __launch_bounds__(256) void mega1(
    const short* __restrict__ Xb, const short* __restrict__ W1t,
    const float* __restrict__ b1, short* __restrict__ h1b,
    const short* __restrict__ Wg1t, const short* __restrict__ W2b,
    short* __restrict__ Wct,
    const float4* __restrict__ cs, float4* __restrict__ cd) {
    __shared__ short As[2][128 * 64];
    __shared__ short Bs[2][64 * 64];
    const int bid = blockIdx.x;
    const int tid = threadIdx.x;

    if (bid < 384) {
        int sw = (bid & 7) * 48 + (bid >> 3);  // XCD swizzle (384%8==0)
        int bx = sw % 12, by = sw / 12;
        gemm_body(Xb, W1t, b1, h1b, H_, K1_, 1, by * 128, bx * 64, As, Bs, tid);
    } else if (bid < 456) {
        int t = bid - 384;                     // 72 blocks: 6 x 12
        int bx = t % 12, by = t / 12;
        // A = Wg1t (rows n of Wct), Bt = W2b row-major (Bt[k][j] = W2[k][j])
        gemm_body(Wg1t, W2b, nullptr, Wct, H_, H_, 0, by * 128, bx * 64, As, Bs, tid);
    } else {
        int lb = bid - 456;                    // 184 copy blocks
        for (size_t i = (size_t)lb * 256 + tid; i < (size_t)SPLIT4_;
             i += (size_t)184 * 256)
            cd[i] = cs[i];
    }
}

// ---------------------------------------------------------------------------
// 3) gate kernel: [0,384) gate partials from gelu(h1@Wct^T+bc)·Wg2;
//                 [384,640) copy overlay of out[SPLIT4, N4)
// ---------------------------------------------------------------------------
__global__ __launch_bounds__(256) void gate_gemm(
    const short* __restrict__ h1b, const short* __restrict__ Wct,
    const float* __restrict__ bc, const float* __restrict__ wg2,
    float* __restrict__ gate_part,
    const float4* __restrict__ cs, float4* __restrict__ cd) {
    __shared__ short As[2][128 * 64];
    __shared__ short Bs[2][64 * 64];
    const int bid = blockIdx.x;
    const int tid = threadIdx.x;

    if (bid >= 384) {
        int lb = bid - 384;                    // 256 copy blocks
        for (size_t i = (size_t)SPLIT4_ + (size_t)lb * 256 + tid; i < (size_t)N4_;
             i += (size_t)256 * 256)
            cd[i] = cs[i];
        return;
    }

    const int lane = tid & 63;
    const int wave = tid >> 6;
    const int llo = lane & 15;
    const int lhi = lane >> 4;
    int sw = (bid & 7) * 48 + (bid >> 3);
    int bx = sw % 12, by = sw / 12;
    const int row0 = by * 128;
    const int col0 = bx * 64;
    const int K = H_;

    const short* gsrc[6];
    short* ldst0[6];
    int lstep[6];
#pragma unroll
    for (int p = 0; p < 6; ++p) {
        int c = wave * 6 + p;
        int jj = lane & 7;
        if (c < 16) {
            int r = c * 8 + (lane >> 3);
            int j = jj ^ (r & 7);
            gsrc[p] = h1b + (size_t)(row0 + r) * K + j * 8;
            ldst0[p] = &As[0][c * 512];
            lstep[p] = 128 * 64;
        } else {
            int r = (c - 16) * 8 + (lane >> 3);
            int j = jj ^ (r & 7);
            gsrc[p] = Wct + (size_t)(col0 + r) * K + j * 8;
            ldst0[p] = &Bs[0][(c - 16) * 512];
            lstep[p] = 64 * 64;
        }
    }

    f32x4 acc[2][4];
#pragma unroll
    for (int mi = 0; mi < 2; ++mi)
#pragma unroll
        for (int nf = 0; nf < 4; ++nf) acc[mi][nf] = (f32x4){0, 0, 0, 0};

    const int nt = K >> 6;
#pragma unroll
    for (int p = 0; p < 6; ++p) GLOAD16(gsrc[p], ldst0[p]);
    __syncthreads();

    for (int t = 0; t < nt; ++t) {
        const int cur = t & 1;
        if (t + 1 < nt) {
#pragma unroll
            for (int p = 0; p < 6; ++p)
                GLOAD16(gsrc[p] + (size_t)(t + 1) * 64,
                        ldst0[p] + (cur ^ 1) * lstep[p]);
        }
        short* Ab = (short*)As[cur];
        short* Bb = (short*)Bs[cur];
#pragma unroll
        for (int ks = 0; ks < 2; ++ks) {
            s16x8 a[2], b[4];
#pragma unroll
            for (int mi = 0; mi < 2; ++mi)
                a[mi] = *(const s16x8*)lds_ptr(Ab, wave * 32 + mi * 16 + llo,
                                               ks * 64 + lhi * 16);
#pragma unroll
            for (int nf = 0; nf < 4; ++nf)
                b[nf] = *(const s16x8*)lds_ptr(Bb, nf * 16 + llo,
                                               ks * 64 + lhi * 16);
#pragma unroll
            for (int mi = 0; mi < 2; ++mi)
#pragma unroll
                for (int nf = 0; nf < 4; ++nf)
                    acc[mi][nf] = __builtin_amdgcn_mfma_f32_16x16x32_bf16(
                        a[mi], b[nf], acc[mi][nf], 0, 0, 0);
        }
        __syncthreads();
    }

    float s[2][4];
#pragma unroll
    for (int mi = 0; mi < 2; ++mi)
#pragma unroll
        for (int j = 0; j < 4; ++j) s[mi][j] = 0.f;
#pragma unroll
    for (int nf = 0; nf < 4; ++nf) {
        int cc = col0 + nf * 16 + llo;
        float bv = bc[cc];
        float wv = wg2[cc];
#pragma unroll
        for (int mi = 0; mi < 2; ++mi)
#pragma unroll
            for (int j = 0; j < 4; ++j)
                s[mi][j] += gelu_exact(acc[mi][nf][j] + bv) * wv;
    }
#pragma unroll
    for (int off = 1; off < 16; off <<= 1)
#pragma unroll
        for (int mi = 0; mi < 2; ++mi)
#pragma unroll
            for (int j = 0; j < 4; ++j)
                s[mi][j] += __shfl_xor(s[mi][j], off);
    if (llo == 0) {
#pragma unroll
        for (int mi = 0; mi < 2; ++mi)
#pragma unroll
            for (int j = 0; j < 4; ++j) {
                int rr = row0 + wave * 32 + mi * 16 + lhi * 4 + j;
                gate_part[(size_t)rr * NCB_ + bx] = s[mi][j];
            }
    }
}

// ---------------------------------------------------------------------------
// 4) final blend: winner rows only (last-write-wins recomputed inline)
// ---------------------------------------------------------------------------
__global__ __launch_bounds__(192) void final_blend(
    const float* __restrict__ vs, const float* __restrict__ iv,
    const int* __restrict__ idx, const float* __restrict__ gate_part,
    const float* __restrict__ bg2, float* __restrict__ out) {
    int r = blockIdx.x;  // b*NI + i
    int b = r >> 3, i = r & 7;
    int id = idx[r];
    if (id < 0 || id >= V_) return;
    for (int j = i + 1; j < NI_; ++j)
        if (idx[b * NI_ + j] == id) return;  // a later valid write wins
    __shared__ float gsh;
    if (threadIdx.x == 0) {
        float s = bg2[0];
#pragma unroll
        for (int c = 0; c < NCB_; ++c) s += gate_part[(size_t)r * NCB_ + c];
        gsh = 1.f / (1.f + expf(-s));
    }
    __syncthreads();
    float g = gsh;
    int t = threadIdx.x;
    const float4* src = (const float4*)(vs + ((size_t)b * V_ + id) * H_);
    const float4* ivr = (const float4*)(iv + (size_t)r * H_);
    float4* dst = (float4*)(out + ((size_t)b * V_ + id) * H_);
    float4 o = src[t], x = ivr[t], res;
    res.x = o.x * (1.f - g) + x.x * g;
    res.y = o.y * (1.f - g) + x.y * g;
    res.z = o.z * (1.f - g) + x.z * g;
    res.w = o.w * (1.f - g) + x.w * g;
    dst[t] = res;
}

// ---------------------------------------------------------------------------
extern "C" void kernel_launch(void* const* d_in, const int* in_sizes, int n_in,
                              void* d_out, int out_size, void* d_ws, size_t ws_size,
                              hipStream_t stream) {
    const float* vs  = (const float*)d_in[0];
    const float* iv  = (const float*)d_in[2];
    const float* W1  = (const float*)d_in[3];
    const float* b1  = (const float*)d_in[4];
    const float* W2  = (const float*)d_in[5];
    const float* b2  = (const float*)d_in[6];
    const float* Wg1 = (const float*)d_in[7];
    const float* bg1 = (const float*)d_in[8];
    const float* Wg2 = (const float*)d_in[9];
    const float* bg2 = (const float*)d_in[10];
    const int*   idx = (const int*)d_in[11];
    float* out = (float*)d_out;

    // workspace layout
    char* ws = (char*)d_ws;
    short* Xb   = (short*)ws;                                   // 12.58 MB
    short* h1b  = (short*)(ws + (size_t)M_ * K1_ * 2);          // 6.29 MB
    float* gate_part = (float*)(ws + (size_t)M_ * K1_ * 2 + (size_t)M_ * H_ * 2);
    short* W1t  = (short*)((char*)gate_part + (size_t)M_ * NCB_ * 4);
    short* W2b  = W1t + (size_t)H_ * K1_;
    short* Wg1t = W2b + (size_t)H_ * H_;
    short* Wct  = Wg1t + (size_t)H_ * H_;
    float* bc   = (float*)(Wct + (size_t)H_ * H_);

    const float4* cs = (const float4*)vs;
    float4* cd = (float4*)out;

    // 1) fused preprocessing (weight converts + gather + bias fold)
    pre_kernel<<<1612, 256, 0, stream>>>(vs, iv, idx, W1, W2, Wg1, b2, bg1,
                                         W1t, W2b, Wg1t, Xb, bc);
    // 2) GEMM1 + Wct (concurrent) + 60% copy
    mega1<<<640, 256, 0, stream>>>(Xb, W1t, b1, h1b, Wg1t, W2b, Wct, cs, cd);
    // 3) gate partials + 40% copy
    gate_gemm<<<640, 256, 0, stream>>>(h1b, Wct, bc, Wg2, gate_part, cs, cd);
    // 4) blend winner rows
    final_blend<<<M_, 192, 0, stream>>>(vs, iv, idx, gate_part, bg2, out);
}